// Round 5
// baseline (342.455 us; speedup 1.0000x reference)
//
#include <hip/hip_runtime.h>
#include <hip/hip_bf16.h>
#include <math.h>

#define N_ENT   40000
#define RANK    200
#define NB      500
#define K_REAL  1000   // RANK*5
#define K_PAD   1024
#define M_PAD   512

typedef __attribute__((ext_vector_type(8))) short       short8;    // 8 bf16 MFMA A/B frag
typedef __attribute__((ext_vector_type(4))) float       f32x4;     // MFMA C/D frag
typedef __attribute__((ext_vector_type(4))) unsigned short ushort4v;
typedef __attribute__((ext_vector_type(8))) unsigned short ushort8v;

__device__ __forceinline__ unsigned short f2bf(float f) {
    union { float f; unsigned int u; } v; v.f = f;
    unsigned int u = v.u;
    return (unsigned short)((u + 0x7FFFu + ((u >> 16) & 1u)) >> 16);  // RNE
}

// async global->LDS 16B: HW semantics = wave-uniform LDS base + lane*16
__device__ __forceinline__ void gld_lds16(const void* g, void* l) {
    __builtin_amdgcn_global_load_lds(
        (const __attribute__((address_space(1))) unsigned int*)g,
        (__attribute__((address_space(3))) unsigned int*)l,
        16, 0, 0);
}

// ---------------------------------------------------------------------------
// ent f32 -> bf16, flat 40M elements; 32B read / 16B write per thread-iter
// ---------------------------------------------------------------------------
__global__ __launch_bounds__(256) void lkg_cvt(
    const float4* __restrict__ in, ushort8v* __restrict__ outv, int n8)
{
    int i = blockIdx.x * 256 + threadIdx.x;
    const int stride = gridDim.x * 256;
    for (; i < n8; i += stride) {
        const float4 a = in[2 * i], b = in[2 * i + 1];
        ushort8v w;
        w[0] = f2bf(a.x); w[1] = f2bf(a.y); w[2] = f2bf(a.z); w[3] = f2bf(a.w);
        w[4] = f2bf(b.x); w[5] = f2bf(b.y); w[6] = f2bf(b.z); w[7] = f2bf(b.w);
        outv[i] = w;
    }
}

// ---------------------------------------------------------------------------
// gather + gelu/rotate/boost/negate -> x bf16 [512][1024] padded; reg_rel f32
// ---------------------------------------------------------------------------
__global__ __launch_bounds__(256) void lkg_prep(
    const int* __restrict__ queries,
    const float* __restrict__ ent,
    const float* __restrict__ rot,
    const float* __restrict__ boo,
    unsigned short* __restrict__ xws,
    float* __restrict__ out)
{
    const int b   = blockIdx.x;
    const int tid = threadIdx.x;
    unsigned short* xrow = xws + (size_t)b * K_PAD;

    if (b >= NB) {                       // zero pad rows 500..511
        ((uint2*)xrow)[tid] = make_uint2(0u, 0u);
        return;
    }
    if (tid >= RANK) {                   // zero K-pad cols 1000..1023
        int c = tid - RANK;
        if (c < K_PAD - K_REAL) xrow[K_REAL + c] = 0;
        return;
    }

    const int d  = tid;
    const int q0 = queries[b * 3 + 0];
    const int q1 = queries[b * 3 + 1];

    const float* L  = ent + (size_t)q0 * (RANK * 5) + d * 5;
    const float* R  = rot + (size_t)q1 * (RANK * 4) + d * 4;
    const float* Bo = boo + (size_t)q1 * (RANK * 4) + d * 4;

    const float t = L[0], r = L[1], i = L[2], j = L[3], k = L[4];
    const float r0 = R[0],  r1 = R[1],  r2 = R[2],  r3 = R[3];
    const float o0 = Bo[0], o1 = Bo[1], o2 = Bo[2], o3 = Bo[3];

    out[(size_t)NB * N_ENT + (size_t)b * RANK + d] =
        sqrtf(r0*r0 + r1*r1 + r2*r2 + r3*r3) +
        sqrtf(o0*o0 + o1*o1 + o2*o2 + o3*o3);

    const float is2 = 0.70710678118654752440f;
    const float rr = 0.5f * r0 * (1.0f + erff(r0 * is2));
    const float ri = 0.5f * r1 * (1.0f + erff(r1 * is2));
    const float rj = 0.5f * r2 * (1.0f + erff(r2 * is2));
    const float rk = 0.5f * r3 * (1.0f + erff(r3 * is2));

    const float s0 = r*rr - i*ri - j*rj - k*rk;
    const float s1 = r*ri + rr*i + j*rk - rj*k;
    const float s2 = r*rj + rr*j + k*ri - rk*i;
    const float s3 = r*rk + rr*k + i*rj - ri*j;

    const float b0 = 0.25f / (1.0f + expf(-o0));
    const float b1 = 0.25f / (1.0f + expf(-o1));
    const float b2 = 0.25f / (1.0f + expf(-o2));
    const float b3 = 0.25f / (1.0f + expf(-o3));

    const float bsq = b0*b0 + b1*b1 + b2*b2 + b3*b3;
    const float xt  = t * bsq + b0*s0 + b1*s1 + b2*s2 + b3*s3;

    const float m00 = sqrtf(1.0f + b0*b0), m11 = sqrtf(1.0f + b1*b1);
    const float m22 = sqrtf(1.0f + b2*b2), m33 = sqrtf(1.0f + b3*b3);
    const float m01 = sqrtf(b0*b1), m02 = sqrtf(b0*b2), m03 = sqrtf(b0*b3);
    const float m12 = sqrtf(b1*b2), m13 = sqrtf(b1*b3), m23 = sqrtf(b2*b3);

    const float xs0 = t*b0 + m00*s0 + m01*s1 + m02*s2 + m03*s3;
    const float xs1 = t*b1 + m01*s0 + m11*s1 + m12*s2 + m13*s3;
    const float xs2 = t*b2 + m02*s0 + m12*s1 + m22*s2 + m23*s3;
    const float xs3 = t*b3 + m03*s0 + m13*s1 + m23*s2 + m33*s3;

    unsigned short* w = xrow + d * 5;
    w[0] = f2bf(-xt);
    w[1] = f2bf(xs0);
    w[2] = f2bf(xs1);
    w[3] = f2bf(xs2);
    w[4] = f2bf(xs3);
}

// ---------------------------------------------------------------------------
// GEMM v3: double-buffered LDS (one barrier/iter), global_load_lds x16 staging,
// LDS-transpose epilogue with 512B-contiguous float4 stores (no out RFO).
// A = xbf [512][1024] bf16 zero-padded; B = ebf [40000][1000] bf16.
// LDS map (shorts): A0 @0, A1 @4096, B0 @8192, B1 @12288  (32 KB total).
// Buffer select by integer offset — pointer-array init of LDS addrspacecast
// does not compile on gfx950.
// Epilogue stores MUST guard the column range: last n-tile (n0=39936) only
// has 64 valid cols; unguarded float4 stores spill into the next row / the
// reg_rel tail (R4 bug).
// ---------------------------------------------------------------------------
__global__ __launch_bounds__(256) void lkg_gemm3(
    const unsigned short* __restrict__ xbf,
    const unsigned short* __restrict__ ebf,
    float* __restrict__ out)
{
    __shared__ __align__(16) unsigned short sm[16384];   // 32 KB

    const int bm  = blockIdx.x;              // m fastest: 4 blocks share B n-tile
    const int n0  = blockIdx.y * 128;
    const int tid = threadIdx.x;
    const int wave = tid >> 6, lane = tid & 63;
    const int wy = wave >> 1, wx = wave & 1;
    const int l15 = lane & 15, quad = lane >> 4;

    f32x4 acc[4][4] = {};

    // stage: chunk c in [0,512) -> row c>>2, 16B col c&3; LDS dest = base + c*16B
    #define STAGE_A(kt, buf)                                                      \
        do {                                                                      \
            _Pragma("unroll")                                                     \
            for (int ii = 0; ii < 2; ++ii) {                                      \
                const int c = tid + ii * 256;                                     \
                gld_lds16(xbf + (size_t)(bm * 128 + (c >> 2)) * K_PAD             \
                              + (kt) * 32 + (c & 3) * 8,                          \
                          (void*)(sm + (buf) * 4096 + c * 8));                    \
            }                                                                     \
        } while (0)

    #define STAGE_B(kt, buf)                                                      \
        do {                                                                      \
            if ((kt) < 31) {                                                      \
                _Pragma("unroll")                                                 \
                for (int ii = 0; ii < 2; ++ii) {                                  \
                    const int c = tid + ii * 256;                                 \
                    gld_lds16(ebf + (size_t)(n0 + (c >> 2)) * K_REAL              \
                                  + (kt) * 32 + (c & 3) * 8,                      \
                              (void*)(sm + 8192 + (buf) * 4096 + c * 8));         \
                }                                                                 \
            } else if (tid < 128) {                                               \
                const ushort8v v = *(const ushort8v*)(                            \
                    ebf + (size_t)(n0 + tid) * K_REAL + 992);                     \
                *(ushort8v*)(sm + 8192 + (buf) * 4096 + tid * 32) = v;            \
            }                                                                     \
        } while (0)

    STAGE_A(0, 0);
    STAGE_B(0, 0);
    __syncthreads();                         // buf0 ready

    for (int kt = 0; kt < 32; ++kt) {
        const int cur = kt & 1;
        if (kt < 31) { STAGE_A(kt + 1, cur ^ 1); STAGE_B(kt + 1, cur ^ 1); }

        const unsigned short* Ab = sm + cur * 4096;
        const unsigned short* Bb = sm + 8192 + cur * 4096;

        short8 a[4], bf[4];
        #pragma unroll
        for (int mi = 0; mi < 4; ++mi)
            a[mi] = *(const short8*)(Ab + (wy * 64 + mi * 16 + l15) * 32 + quad * 8);
        #pragma unroll
        for (int ni = 0; ni < 4; ++ni)
            bf[ni] = *(const short8*)(Bb + (wx * 64 + ni * 16 + l15) * 32 + quad * 8);

        #pragma unroll
        for (int mi = 0; mi < 4; ++mi)
            #pragma unroll
            for (int ni = 0; ni < 4; ++ni)
                acc[mi][ni] = __builtin_amdgcn_mfma_f32_16x16x32_bf16(
                    a[mi], bf[ni], acc[mi][ni], 0, 0, 0);

        __syncthreads();                     // drains next-tile loads + guards reuse
    }
    #undef STAGE_A
    #undef STAGE_B

    // ---- epilogue: LDS transpose, 512B-contiguous float4 stores ----
    const int EPLD = 132;                    // +4 pad: <=2-way bank aliasing (free)
    float* ep = (float*)sm;                  // 32*132*4 = 16896 B <= 32768
    #pragma unroll
    for (int mi = 0; mi < 4; ++mi) {
        if (mi) __syncthreads();             // prior read phase done before overwrite
        #pragma unroll
        for (int ni = 0; ni < 4; ++ni)
            #pragma unroll
            for (int r = 0; r < 4; ++r)
                ep[(wy * 16 + quad * 4 + r) * EPLD + wx * 64 + ni * 16 + l15] =
                    acc[mi][ni][r];
        __syncthreads();
        #pragma unroll
        for (int p = 0; p < 4; ++p) {
            const int lrow = (tid >> 5) + p * 8;     // 0..31
            const int col  = (tid & 31) * 4;
            const int wyy = lrow >> 4, within = lrow & 15;
            const int grow = bm * 128 + wyy * 64 + mi * 16 + within;
            // N_ENT % 4 == 0 -> each float4 is entirely in- or out-of-bounds
            if (grow < NB && n0 + col < N_ENT) {
                const float4 v = *(const float4*)(ep + lrow * EPLD + col);
                float4 o;
                o.x = 2.0f + 0.01f * v.x; o.y = 2.0f + 0.01f * v.y;
                o.z = 2.0f + 0.01f * v.z; o.w = 2.0f + 0.01f * v.w;
                *(float4*)(out + (size_t)grow * N_ENT + n0 + col) = o;
            }
        }
    }
}

// ---------------------------------------------------------------------------
// Fallback GEMM (round-1 style) for small ws_size.
// ---------------------------------------------------------------------------
__global__ __launch_bounds__(256) void lkg_gemm(
    const unsigned short* __restrict__ xws,
    const float* __restrict__ ent,
    float* __restrict__ out)
{
    __shared__ unsigned short As[128 * 32];
    __shared__ unsigned short Bs[128 * 32];

    const int bm  = blockIdx.x;
    const int n0  = blockIdx.y * 128;
    const int tid = threadIdx.x;
    const int wave = tid >> 6, lane = tid & 63;
    const int wy = wave >> 1, wx = wave & 1;
    const int l15 = lane & 15, quad = lane >> 4;

    f32x4 acc[4][4] = {};

    for (int kt = 0; kt < K_PAD / 32; ++kt) {
        #pragma unroll
        for (int ii = 0; ii < 2; ++ii) {
            const int c   = tid + ii * 256;
            const int row = c >> 2, col = c & 3;
            const ushort8v v = *(const ushort8v*)(
                xws + (size_t)(bm * 128 + row) * K_PAD + kt * 32 + col * 8);
            *(ushort8v*)(As + row * 32 + col * 8) = v;
        }
        #pragma unroll
        for (int ii = 0; ii < 4; ++ii) {
            const int c   = tid + ii * 256;
            const int row = c >> 3, cc = c & 7;
            const int n = n0 + row;
            const int k = kt * 32 + cc * 4;
            float4 v = make_float4(0.f, 0.f, 0.f, 0.f);
            if (n < N_ENT && k < K_REAL)
                v = *(const float4*)(ent + (size_t)n * K_REAL + k);
            ushort4v w;
            w.x = f2bf(v.x); w.y = f2bf(v.y); w.z = f2bf(v.z); w.w = f2bf(v.w);
            *(ushort4v*)(Bs + row * 32 + cc * 4) = w;
        }
        __syncthreads();

        short8 a[4], bf[4];
        #pragma unroll
        for (int mi = 0; mi < 4; ++mi)
            a[mi] = *(const short8*)(As + (wy * 64 + mi * 16 + l15) * 32 + quad * 8);
        #pragma unroll
        for (int ni = 0; ni < 4; ++ni)
            bf[ni] = *(const short8*)(Bs + (wx * 64 + ni * 16 + l15) * 32 + quad * 8);

        #pragma unroll
        for (int mi = 0; mi < 4; ++mi)
            #pragma unroll
            for (int ni = 0; ni < 4; ++ni)
                acc[mi][ni] = __builtin_amdgcn_mfma_f32_16x16x32_bf16(
                    a[mi], bf[ni], acc[mi][ni], 0, 0, 0);
        __syncthreads();
    }

    #pragma unroll
    for (int mi = 0; mi < 4; ++mi) {
        const int gmb = bm * 128 + wy * 64 + mi * 16 + quad * 4;
        #pragma unroll
        for (int ni = 0; ni < 4; ++ni) {
            const int gn = n0 + wx * 64 + ni * 16 + l15;
            #pragma unroll
            for (int rr2 = 0; rr2 < 4; ++rr2) {
                const int gm = gmb + rr2;
                if (gm < NB && gn < N_ENT)
                    out[(size_t)gm * N_ENT + gn] = 2.0f + acc[mi][ni][rr2] * 0.01f;
            }
        }
    }
}

extern "C" void kernel_launch(void* const* d_in, const int* in_sizes, int n_in,
                              void* d_out, int out_size, void* d_ws, size_t ws_size,
                              hipStream_t stream) {
    const int*   queries = (const int*)d_in[0];
    const float* ent     = (const float*)d_in[1];
    const float* rot     = (const float*)d_in[2];
    const float* boo     = (const float*)d_in[3];
    float*       out     = (float*)d_out;

    const size_t NEED = (size_t)N_ENT * K_REAL * 2 + (size_t)M_PAD * K_PAD * 2; // ~81 MB

    if (ws_size >= NEED) {
        unsigned short* ebf = (unsigned short*)d_ws;                 // [40000][1000] bf16
        unsigned short* xbf = ebf + (size_t)N_ENT * K_REAL;          // [512][1024] bf16
        lkg_cvt<<<4096, 256, 0, stream>>>((const float4*)ent, (ushort8v*)ebf,
                                          N_ENT * K_REAL / 8);
        lkg_prep<<<M_PAD, 256, 0, stream>>>(queries, ent, rot, boo, xbf, out);
        lkg_gemm3<<<dim3(4, (N_ENT + 127) / 128), 256, 0, stream>>>(xbf, ebf, out);
    } else {
        unsigned short* xws = (unsigned short*)d_ws;
        lkg_prep<<<M_PAD, 256, 0, stream>>>(queries, ent, rot, boo, xws, out);
        lkg_gemm<<<dim3(4, (N_ENT + 127) / 128), 256, 0, stream>>>(xws, ent, out);
    }
}

// Round 6
// 338.738 us; speedup vs baseline: 1.0110x; 1.0110x over previous
//
#include <hip/hip_runtime.h>
#include <hip/hip_bf16.h>
#include <math.h>

#define N_ENT   40000
#define RANK    200
#define NB      500
#define K_REAL  1000   // RANK*5
#define K_PAD   1024
#define M_PAD   512

typedef __attribute__((ext_vector_type(8))) short       short8;    // 8 bf16 MFMA A/B frag
typedef __attribute__((ext_vector_type(4))) float       f32x4;     // MFMA C/D frag
typedef __attribute__((ext_vector_type(8))) unsigned short ushort8v;

__device__ __forceinline__ unsigned short f2bf(float f) {
    union { float f; unsigned int u; } v; v.f = f;
    unsigned int u = v.u;
    return (unsigned short)((u + 0x7FFFu + ((u >> 16) & 1u)) >> 16);  // RNE
}

// truncating bf16x2 pack: low half from x, high half from y
__device__ __forceinline__ unsigned int pack_hi(float x, float y) {
    return (__float_as_uint(x) >> 16) | (__float_as_uint(y) & 0xFFFF0000u);
}

// async global->LDS 16B: HW writes wave-uniform LDS base + lane*16
__device__ __forceinline__ void gld_lds16(const void* g, void* l) {
    __builtin_amdgcn_global_load_lds(
        (const __attribute__((address_space(1))) unsigned int*)g,
        (__attribute__((address_space(3))) unsigned int*)l,
        16, 0, 0);
}

// ---------------------------------------------------------------------------
// gather + gelu/rotate/boost/negate -> x bf16 [512][1024] padded; reg_rel f32
// ---------------------------------------------------------------------------
__global__ __launch_bounds__(256) void lkg_prep(
    const int* __restrict__ queries,
    const float* __restrict__ ent,
    const float* __restrict__ rot,
    const float* __restrict__ boo,
    unsigned short* __restrict__ xws,
    float* __restrict__ out)
{
    const int b   = blockIdx.x;
    const int tid = threadIdx.x;
    unsigned short* xrow = xws + (size_t)b * K_PAD;

    if (b >= NB) {                       // zero pad rows 500..511
        ((uint2*)xrow)[tid] = make_uint2(0u, 0u);
        return;
    }
    if (tid >= RANK) {                   // zero K-pad cols 1000..1023
        int c = tid - RANK;
        if (c < K_PAD - K_REAL) xrow[K_REAL + c] = 0;
        return;
    }

    const int d  = tid;
    const int q0 = queries[b * 3 + 0];
    const int q1 = queries[b * 3 + 1];

    const float* L  = ent + (size_t)q0 * (RANK * 5) + d * 5;
    const float* R  = rot + (size_t)q1 * (RANK * 4) + d * 4;
    const float* Bo = boo + (size_t)q1 * (RANK * 4) + d * 4;

    const float t = L[0], r = L[1], i = L[2], j = L[3], k = L[4];
    const float r0 = R[0],  r1 = R[1],  r2 = R[2],  r3 = R[3];
    const float o0 = Bo[0], o1 = Bo[1], o2 = Bo[2], o3 = Bo[3];

    out[(size_t)NB * N_ENT + (size_t)b * RANK + d] =
        sqrtf(r0*r0 + r1*r1 + r2*r2 + r3*r3) +
        sqrtf(o0*o0 + o1*o1 + o2*o2 + o3*o3);

    const float is2 = 0.70710678118654752440f;
    const float rr = 0.5f * r0 * (1.0f + erff(r0 * is2));
    const float ri = 0.5f * r1 * (1.0f + erff(r1 * is2));
    const float rj = 0.5f * r2 * (1.0f + erff(r2 * is2));
    const float rk = 0.5f * r3 * (1.0f + erff(r3 * is2));

    const float s0 = r*rr - i*ri - j*rj - k*rk;
    const float s1 = r*ri + rr*i + j*rk - rj*k;
    const float s2 = r*rj + rr*j + k*ri - rk*i;
    const float s3 = r*rk + rr*k + i*rj - ri*j;

    const float b0 = 0.25f / (1.0f + expf(-o0));
    const float b1 = 0.25f / (1.0f + expf(-o1));
    const float b2 = 0.25f / (1.0f + expf(-o2));
    const float b3 = 0.25f / (1.0f + expf(-o3));

    const float bsq = b0*b0 + b1*b1 + b2*b2 + b3*b3;
    const float xt  = t * bsq + b0*s0 + b1*s1 + b2*s2 + b3*s3;

    const float m00 = sqrtf(1.0f + b0*b0), m11 = sqrtf(1.0f + b1*b1);
    const float m22 = sqrtf(1.0f + b2*b2), m33 = sqrtf(1.0f + b3*b3);
    const float m01 = sqrtf(b0*b1), m02 = sqrtf(b0*b2), m03 = sqrtf(b0*b3);
    const float m12 = sqrtf(b1*b2), m13 = sqrtf(b1*b3), m23 = sqrtf(b2*b3);

    const float xs0 = t*b0 + m00*s0 + m01*s1 + m02*s2 + m03*s3;
    const float xs1 = t*b1 + m01*s0 + m11*s1 + m12*s2 + m13*s3;
    const float xs2 = t*b2 + m02*s0 + m12*s1 + m22*s2 + m23*s3;
    const float xs3 = t*b3 + m03*s0 + m13*s1 + m23*s2 + m33*s3;

    unsigned short* w = xrow + d * 5;
    w[0] = f2bf(-xt);
    w[1] = f2bf(xs0);
    w[2] = f2bf(xs1);
    w[3] = f2bf(xs2);
    w[4] = f2bf(xs3);
}

// ---------------------------------------------------------------------------
// GEMM v4: no pre-conversion pass. A = xbf (bf16, ws); B = ent (f32, input)
// staged raw via global_load_lds and truncate-packed to bf16 at frag-read.
// XOR chunk swizzles (applied on the GLOBAL address, LDS stays lane-contiguous
// as global_load_lds requires) kill frag-read bank conflicts:
//   A: chunk cc stores k-chunk cc ^ ((row>>1)&3)   -> 2-way reads (free)
//   B: chunk cc stores k-chunk cc ^ (row&7)        -> 2-way reads (free)
// Single-buffered 2-barrier loop (dbuf measured neutral in R5).
// LDS: A 8 KB @0, B-f32 16 KB @8192 -> 24 KB, 6 blocks/CU.
// B rows >= 40000 clamp the global address (reads past ent would be OOB).
// ---------------------------------------------------------------------------
__global__ __launch_bounds__(256) void lkg_gemm4(
    const unsigned short* __restrict__ xbf,
    const float* __restrict__ ent,
    float* __restrict__ out)
{
    __shared__ __align__(16) unsigned char smx[24576];
    unsigned short* As  = (unsigned short*)smx;          // [128][32] bf16, swizzled
    float*          Bsf = (float*)(smx + 8192);          // [128][32] f32,  swizzled

    const int bm  = blockIdx.x;              // m fastest: 4 blocks share B n-tile
    const int n0  = blockIdx.y * 128;
    const int tid = threadIdx.x;
    const int wave = tid >> 6, lane = tid & 63;
    const int wy = wave >> 1, wx = wave & 1;
    const int l15 = lane & 15, quad = lane >> 4;

    f32x4 acc[4][4] = {};

    for (int kt = 0; kt < 32; ++kt) {
        // stage A: 512 x 16B chunks; chunk c -> row c>>2, slot c&3; LDS = c*16B
        #pragma unroll
        for (int ii = 0; ii < 2; ++ii) {
            const int c = tid + ii * 256;
            const int row = c >> 2, cc = c & 3;
            const int ksw = cc ^ ((row >> 1) & 3);       // k-chunk stored in slot cc
            gld_lds16(xbf + (size_t)(bm * 128 + row) * K_PAD + kt * 32 + ksw * 8,
                      (void*)(As + c * 8));
        }
        // stage B: 1024 x 16B chunks of f32; chunk c -> row c>>3, slot c&7
        if (kt < 31) {
            #pragma unroll
            for (int ii = 0; ii < 4; ++ii) {
                const int c = tid + ii * 256;
                const int row = c >> 3, cc = c & 7;
                const int ksw = cc ^ (row & 7);
                const int gr  = (n0 + row < N_ENT) ? (n0 + row) : (N_ENT - 1);
                gld_lds16(ent + (size_t)gr * K_REAL + kt * 32 + ksw * 4,
                          (void*)(Bsf + c * 4));
            }
        } else if (tid < 128) {
            // tail kt=31: k=992..999 (2 f32 chunks/row); A cols k>=1000 are zero
            const int row = tid;
            const int gr  = (n0 + row < N_ENT) ? (n0 + row) : (N_ENT - 1);
            const float4 v0 = *(const float4*)(ent + (size_t)gr * K_REAL + 992);
            const float4 v1 = *(const float4*)(ent + (size_t)gr * K_REAL + 996);
            *(float4*)(Bsf + row * 32 + (0 ^ (row & 7)) * 4) = v0;
            *(float4*)(Bsf + row * 32 + (1 ^ (row & 7)) * 4) = v1;
        }
        __syncthreads();

        short8 a[4], bfr[4];
        #pragma unroll
        for (int mi = 0; mi < 4; ++mi) {
            const int row = wy * 64 + mi * 16 + l15;
            a[mi] = *(const short8*)(As + row * 32 + (quad ^ ((row >> 1) & 3)) * 8);
        }
        #pragma unroll
        for (int ni = 0; ni < 4; ++ni) {
            const int row = wx * 64 + ni * 16 + l15;
            const int sw  = row & 7;
            const float4 c0 = *(const float4*)(Bsf + row * 32 + ((2 * quad)     ^ sw) * 4);
            const float4 c1 = *(const float4*)(Bsf + row * 32 + ((2 * quad + 1) ^ sw) * 4);
            union { unsigned int u[4]; short8 s; } pk;
            pk.u[0] = pack_hi(c0.x, c0.y);
            pk.u[1] = pack_hi(c0.z, c0.w);
            pk.u[2] = pack_hi(c1.x, c1.y);
            pk.u[3] = pack_hi(c1.z, c1.w);
            bfr[ni] = pk.s;
        }

        #pragma unroll
        for (int mi = 0; mi < 4; ++mi)
            #pragma unroll
            for (int ni = 0; ni < 4; ++ni)
                acc[mi][ni] = __builtin_amdgcn_mfma_f32_16x16x32_bf16(
                    a[mi], bfr[ni], acc[mi][ni], 0, 0, 0);

        __syncthreads();
    }

    // ---- epilogue: LDS transpose, 512B-contiguous float4 stores (no RFO) ----
    const int EPLD = 132;                    // +4 pad: <=2-way bank aliasing (free)
    float* ep = (float*)smx;                 // 32*132*4 = 16896 B <= 24576
    #pragma unroll
    for (int mi = 0; mi < 4; ++mi) {
        if (mi) __syncthreads();             // prior read phase done before overwrite
        #pragma unroll
        for (int ni = 0; ni < 4; ++ni)
            #pragma unroll
            for (int r = 0; r < 4; ++r)
                ep[(wy * 16 + quad * 4 + r) * EPLD + wx * 64 + ni * 16 + l15] =
                    acc[mi][ni][r];
        __syncthreads();
        #pragma unroll
        for (int p = 0; p < 4; ++p) {
            const int lrow = (tid >> 5) + p * 8;     // 0..31
            const int col  = (tid & 31) * 4;
            const int wyy = lrow >> 4, within = lrow & 15;
            const int grow = bm * 128 + wyy * 64 + mi * 16 + within;
            // N_ENT % 4 == 0 -> each float4 is entirely in- or out-of-bounds
            if (grow < NB && n0 + col < N_ENT) {
                const float4 v = *(const float4*)(ep + lrow * EPLD + col);
                float4 o;
                o.x = 2.0f + 0.01f * v.x; o.y = 2.0f + 0.01f * v.y;
                o.z = 2.0f + 0.01f * v.z; o.w = 2.0f + 0.01f * v.w;
                *(float4*)(out + (size_t)grow * N_ENT + n0 + col) = o;
            }
        }
    }
}

extern "C" void kernel_launch(void* const* d_in, const int* in_sizes, int n_in,
                              void* d_out, int out_size, void* d_ws, size_t ws_size,
                              hipStream_t stream) {
    const int*   queries = (const int*)d_in[0];
    const float* ent     = (const float*)d_in[1];
    const float* rot     = (const float*)d_in[2];
    const float* boo     = (const float*)d_in[3];
    float*       out     = (float*)d_out;
    unsigned short* xbf  = (unsigned short*)d_ws;   // [512][1024] bf16 = 1 MB

    lkg_prep<<<M_PAD, 256, 0, stream>>>(queries, ent, rot, boo, xbf, out);
    lkg_gemm4<<<dim3(4, (N_ENT + 127) / 128), 256, 0, stream>>>(xbf, ent, out);
}